// Round 6
// baseline (193.750 us; speedup 1.0000x reference)
//
#include <hip/hip_runtime.h>
#include <hip/hip_bf16.h>
#include <stdint.h>

#define MDIM 8192
#define KDIM 1024
#define NDIM 1024
#define NEXP 8
#define BM 128
#define BN 128
#define BK 32   // fp32 slab: 128 rows x 32 k x 4B = 16 KB per matrix per buffer

typedef __attribute__((ext_vector_type(8))) short bf16x8;
typedef __attribute__((ext_vector_type(4))) float floatx4;

// ---- fp32 -> packed 2x bf16 (RNE). gfx950 has v_cvt_pk_bf16_f32; fallback is manual RNE.
#if __has_builtin(__builtin_amdgcn_cvt_pk_bf16_f32)
typedef __attribute__((ext_vector_type(2))) __bf16 bf16x2v;
static __device__ __forceinline__ int cvt2(float x, float y) {
    bf16x2v r = __builtin_amdgcn_cvt_pk_bf16_f32(x, y);  // r[0]=cvt(x) -> low 16 bits
    return __builtin_bit_cast(int, r);
}
#else
static __device__ __forceinline__ unsigned short f2b(float f) {
    unsigned int u = __float_as_uint(f);
    return (unsigned short)((u + 0x7fffu + ((u >> 16) & 1u)) >> 16);
}
static __device__ __forceinline__ int cvt2(float x, float y) {
    return (int)f2b(x) | ((int)f2b(y) << 16);
}
#endif

static __device__ __forceinline__ bf16x8 pack8(float4 a, float4 b) {
    int4 r;
    r.x = cvt2(a.x, a.y);
    r.y = cvt2(a.z, a.w);
    r.z = cvt2(b.x, b.y);
    r.w = cvt2(b.z, b.w);
    return __builtin_bit_cast(bf16x8, r);
}

#define GLDS(gp, lp) __builtin_amdgcn_global_load_lds(                        \
    (const __attribute__((address_space(1))) unsigned int*)(gp),              \
    (__attribute__((address_space(3))) unsigned int*)(lp), 16, 0, 0)

// Single fused kernel: stage fp32 tiles via global_load_lds (dbuf, XOR-swizzled
// 16B chunks), convert fp32->bf16 at fragment read (v_cvt_pk co-issues with
// MFMA pipe, fills the barrier-drain stall budget), 16x16x32 bf16 MFMA.
//
// LDS row layout: 128 rows x 8 chunks of 16B; position p of row r holds global
// chunk p^(r&7). Frag (8 fp32 at k=quad*8) = global chunks {2q, 2q+1} -> LDS
// positions (2q)^(r&7), (2q+1)^(r&7): bank-spread across fr (2-way = free).
__global__ __launch_bounds__(256, 2)
void grouped_gemm_f32(const float* __restrict__ A,   // [M,K] fp32
                      const float* __restrict__ B,   // [E,N,K] fp32
                      const int* __restrict__ seg_indptr,
                      const int* __restrict__ widx,
                      float* __restrict__ c)
{
    __shared__ float As0[BM * BK], As1[BM * BK];   // 16 KB each
    __shared__ float Bs0[BN * BK], Bs1[BN * BK];   // 64 KB total -> 2 blocks/CU (= grid cap)

    // XCD swizzle: 568 = 8*71; consecutive bids (same m-slab, all n-tiles) share an XCD L2
    const int bid = ((int)blockIdx.x & 7) * 71 + ((int)blockIdx.x >> 3);

    const int NTN = NDIM / BN;  // 8
    int rem = bid;
    int s = -1, m0 = 0, seg_end = 0, n0 = 0;
    for (int i = 0; i < NEXP; ++i) {
        int ps = seg_indptr[i], pe = seg_indptr[i + 1];
        int nt = ((pe - ps + BM - 1) / BM) * NTN;
        if (rem < nt) { s = i; m0 = ps + (rem / NTN) * BM; n0 = (rem % NTN) * BN; seg_end = pe; break; }
        rem -= nt;
    }
    if (s < 0) return;  // surplus block (worst-case grid)

    const float* __restrict__ be = B + (size_t)widx[s] * (size_t)(NDIM * KDIM);

    const int tid  = (int)threadIdx.x;
    const int wave = tid >> 6;
    const int lane = tid & 63;

    // staging: call j stages rows [j*32, j*32+32); thread -> row j*32 + tid/8,
    // LDS chunk-pos tid&7, global chunk (tid&7)^(srow&7). 16B/lane, full 128B lines.
    const int srow = tid >> 3;                       // 0..31
    const int gch  = ((tid & 7) ^ (srow & 7)) * 4;   // float offset of swizzled 16B chunk
    const float* ap[4];
    const float* bp[4];
#pragma unroll
    for (int j = 0; j < 4; ++j) {
        int ra = m0 + j * 32 + srow; if (ra >= MDIM) ra = MDIM - 1;  // clamp; masked at store
        ap[j] = A  + (size_t)ra * KDIM + gch;
        bp[j] = be + (size_t)(n0 + j * 32 + srow) * KDIM + gch;
    }
    const int ldso = wave * 256;   // floats: wave stages 8 rows x 32 floats; HW adds lane*16B

    const int wm = (wave & 1) * 64;
    const int wn = (wave >> 1) * 64;
    const int fr   = lane & 15;
    const int quad = lane >> 4;
    const int p0 = ((2 * quad) ^ (fr & 7)) * 4;      // float offsets of the frag's two 16B pieces
    const int p1 = ((2 * quad + 1) ^ (fr & 7)) * 4;

    floatx4 acc[4][4] = {};

#define STAGE(AS, BS, kk)                                                     \
    do {                                                                      \
        _Pragma("unroll")                                                     \
        for (int j = 0; j < 4; ++j) {                                         \
            GLDS(ap[j] + (kk), &AS[j * 1024 + ldso]);                         \
            GLDS(bp[j] + (kk), &BS[j * 1024 + ldso]);                         \
        }                                                                     \
    } while (0)

#define COMPUTE(AS, BS)                                                       \
    do {                                                                      \
        bf16x8 af[4], bf[4];                                                  \
        _Pragma("unroll")                                                     \
        for (int mi = 0; mi < 4; ++mi) {                                      \
            const int base = (wm + mi * 16 + fr) * BK;                        \
            af[mi] = pack8(*reinterpret_cast<const float4*>(&AS[base + p0]),  \
                           *reinterpret_cast<const float4*>(&AS[base + p1])); \
        }                                                                     \
        _Pragma("unroll")                                                     \
        for (int ni = 0; ni < 4; ++ni) {                                      \
            const int base = (wn + ni * 16 + fr) * BK;                        \
            bf[ni] = pack8(*reinterpret_cast<const float4*>(&BS[base + p0]),  \
                           *reinterpret_cast<const float4*>(&BS[base + p1])); \
        }                                                                     \
        _Pragma("unroll")                                                     \
        for (int mi = 0; mi < 4; ++mi)                                        \
            _Pragma("unroll")                                                 \
            for (int ni = 0; ni < 4; ++ni)                                    \
                acc[mi][ni] = __builtin_amdgcn_mfma_f32_16x16x32_bf16(        \
                    af[mi], bf[ni], acc[mi][ni], 0, 0, 0);                    \
    } while (0)

    STAGE(As0, Bs0, 0);                     // prologue: slab 0 -> buf0
#pragma unroll 1
    for (int ii = 0; ii < 16; ++ii) {       // 32 slabs, 2 per iteration
        const int i0 = ii * 2;
        __syncthreads();                    // drains buf0's loads (flew during prior compute)
        STAGE(As1, Bs1, (i0 + 1) * BK);     // slab i0+1 -> buf1 (i0 <= 30, always valid)
        COMPUTE(As0, Bs0);
        __syncthreads();                    // drains buf1's loads
        if (i0 + 2 < 32) STAGE(As0, Bs0, (i0 + 2) * BK);
        COMPUTE(As1, Bs1);
    }

    // epilogue: C/D layout col=lane&15, row=quad*4+reg (m89-verified); mask partial rows
#pragma unroll
    for (int mi = 0; mi < 4; ++mi) {
        const int rbase = m0 + wm + mi * 16 + quad * 4;
#pragma unroll
        for (int ni = 0; ni < 4; ++ni) {
            const int col = n0 + wn + ni * 16 + fr;
#pragma unroll
            for (int j = 0; j < 4; ++j) {
                const int row = rbase + j;
                if (row < seg_end)
                    c[(size_t)row * NDIM + col] = acc[mi][ni][j];
            }
        }
    }
#undef STAGE
#undef COMPUTE
}

extern "C" void kernel_launch(void* const* d_in, const int* in_sizes, int n_in,
                              void* d_out, int out_size, void* d_ws, size_t ws_size,
                              hipStream_t stream) {
    const float* a          = (const float*)d_in[0];
    const float* b          = (const float*)d_in[1];
    // d_in[2]=c (zeros; fully overwritten), d_in[3]=batch_size, d_in[4]=weight_column_major: unused
    const int*   seg_indptr = (const int*)d_in[5];
    const int*   widx       = (const int*)d_in[6];
    float*       out        = (float*)d_out;

    // worst-case tiles: (64+7) row-tiles x 8 n-tiles = 568 = 8*71 (XCD swizzle bijective)
    hipLaunchKernelGGL(grouped_gemm_f32, dim3(568), dim3(256), 0, stream,
                       a, b, seg_indptr, widx, out);
}

// Round 7
// 172.544 us; speedup vs baseline: 1.1229x; 1.1229x over previous
//
#include <hip/hip_runtime.h>
#include <hip/hip_bf16.h>
#include <stdint.h>

#define MDIM 8192
#define KDIM 1024
#define NDIM 1024
#define NEXP 8
#define BM 128
#define BN 128
#define BK 64          // bf16 slab: 128 rows x 64 k x 2B = 16 KB per matrix per buffer
#define PGRID 512      // persistent grid: exactly 2 blocks/CU (64 KB LDS cap)

typedef __attribute__((ext_vector_type(8))) short bf16x8;
typedef __attribute__((ext_vector_type(4))) float floatx4;
typedef __attribute__((ext_vector_type(8))) unsigned short ushort8;

static __device__ __forceinline__ unsigned short f2b(float f) {
    // fp32 -> bf16 round-to-nearest-even (inputs finite)
    unsigned int u = __float_as_uint(f);
    return (unsigned short)((u + 0x7fffu + ((u >> 16) & 1u)) >> 16);
}

// ---------------- pass 1: fp32 -> bf16 (a and b) into workspace ----------------
// 16,777,216 elems, 8/thread -> 8192 blocks x 256 (exact). ~96 MB => ~15.5 us (HBM floor).
__global__ __launch_bounds__(256)
void cvt_bf16(const float* __restrict__ a, const float* __restrict__ b,
              unsigned short* __restrict__ wa, unsigned short* __restrict__ wb)
{
    const long t  = (long)blockIdx.x * 256 + threadIdx.x;
    const long NA = (long)MDIM * KDIM / 8;
    const float* src; unsigned short* dst; long v;
    if (t < NA) { src = a; dst = wa; v = t; }
    else        { src = b; dst = wb; v = t - NA; }
    const float4 lo = ((const float4*)src)[2 * v];
    const float4 hi = ((const float4*)src)[2 * v + 1];
    ushort8 o;
    o[0] = f2b(lo.x); o[1] = f2b(lo.y); o[2] = f2b(lo.z); o[3] = f2b(lo.w);
    o[4] = f2b(hi.x); o[5] = f2b(hi.y); o[6] = f2b(hi.z); o[7] = f2b(hi.w);
    ((ushort8*)dst)[v] = o;
}

// ---------------- pass 2: persistent bf16 GEMM, 128x128x64, dbuf, swizzled -----
#define GLDS(gp, lp) __builtin_amdgcn_global_load_lds(                        \
    (const __attribute__((address_space(1))) unsigned int*)(gp),              \
    (__attribute__((address_space(3))) unsigned int*)(lp), 16, 0, 0)

__global__ __launch_bounds__(256, 2)
void grouped_gemm_v7(const unsigned short* __restrict__ A,   // [M,K] bf16
                     const unsigned short* __restrict__ B,   // [E,N,K] bf16
                     const int* __restrict__ seg_indptr,
                     const int* __restrict__ widx,
                     float* __restrict__ c,
                     int* __restrict__ steal_cnt)            // zeroed on-stream pre-launch
{
    __shared__ unsigned short As0[BM * BK], As1[BM * BK];   // 16 KB each
    __shared__ unsigned short Bs0[BN * BK], Bs1[BN * BK];   // 64 KB -> 2 blocks/CU

    const int tid  = (int)threadIdx.x;
    const int wave = tid >> 6;
    const int lane = tid & 63;
    const int srow = tid >> 3;                       // staging row within 32-row group
    const int gch  = ((tid & 7) ^ (srow & 7)) * 8;   // XOR-swizzled 16B chunk (bf16 offset)
    const int ldso = wave * 512;                     // wave-uniform LDS offset (elements)
    const int wm   = (wave & 1) * 64;
    const int wn   = (wave >> 1) * 64;
    const int fr   = lane & 15;
    const int quad = lane >> 4;
    const int fro0 = ((0 * 4 + quad) ^ (fr & 7)) * 8;  // frag offsets in 8-chunk row
    const int fro1 = ((1 * 4 + quad) ^ (fr & 7)) * 8;

    // total tile count (<= (64+7)*8 = 568)
    int ntiles = 0;
#pragma unroll
    for (int i = 0; i < NEXP; ++i)
        ntiles += ((seg_indptr[i + 1] - seg_indptr[i] + BM - 1) / BM) * (NDIM / BN);

    __shared__ int next_tile_sh;

    int tile = (int)blockIdx.x;   // static first tile
    while (tile < ntiles) {
        // ---- decode tile -> (segment, m0, n0)
        int rem = tile, s = 0, m0 = 0, seg_end = 0, n0 = 0;
        for (int i = 0; i < NEXP; ++i) {
            int ps = seg_indptr[i], pe = seg_indptr[i + 1];
            int nt = ((pe - ps + BM - 1) / BM) * (NDIM / BN);
            if (rem < nt) { s = i; m0 = ps + (rem / (NDIM / BN)) * BM; n0 = (rem % (NDIM / BN)) * BN; seg_end = pe; break; }
            rem -= nt;
        }
        const unsigned short* __restrict__ be = B + (size_t)widx[s] * (size_t)(NDIM * KDIM);

        const unsigned short* ap[4];
        const unsigned short* bp[4];
#pragma unroll
        for (int j = 0; j < 4; ++j) {
            int ra = m0 + j * 32 + srow; if (ra >= MDIM) ra = MDIM - 1;  // clamp; masked at store
            ap[j] = A  + (size_t)ra * KDIM + gch;
            bp[j] = be + (size_t)(n0 + j * 32 + srow) * KDIM + gch;
        }

        floatx4 acc[4][4] = {};

#define STAGE(AS, BS, kk)                                                     \
        do {                                                                  \
            _Pragma("unroll")                                                 \
            for (int j = 0; j < 4; ++j) {                                     \
                GLDS(ap[j] + (kk), &AS[j * 2048 + ldso]);                     \
                GLDS(bp[j] + (kk), &BS[j * 2048 + ldso]);                     \
            }                                                                 \
        } while (0)

#define COMPUTE(AS, BS)                                                       \
        do {                                                                  \
            bf16x8 af[4], bf[4];                                              \
            _Pragma("unroll")                                                 \
            for (int h = 0; h < 2; ++h) {                                     \
                const int fro = h ? fro1 : fro0;                              \
                _Pragma("unroll")                                             \
                for (int mi = 0; mi < 4; ++mi)                                \
                    af[mi] = *reinterpret_cast<const bf16x8*>(                \
                        &AS[(wm + mi * 16 + fr) * BK + fro]);                 \
                _Pragma("unroll")                                             \
                for (int ni = 0; ni < 4; ++ni)                                \
                    bf[ni] = *reinterpret_cast<const bf16x8*>(                \
                        &BS[(wn + ni * 16 + fr) * BK + fro]);                 \
                _Pragma("unroll")                                             \
                for (int mi = 0; mi < 4; ++mi)                                \
                    _Pragma("unroll")                                         \
                    for (int ni = 0; ni < 4; ++ni)                            \
                        acc[mi][ni] = __builtin_amdgcn_mfma_f32_16x16x32_bf16(\
                            af[mi], bf[ni], acc[mi][ni], 0, 0, 0);            \
            }                                                                 \
        } while (0)

        STAGE(As0, Bs0, 0);                 // prologue: slab 0 -> buf0
#pragma unroll 1
        for (int ii = 0; ii < 8; ++ii) {    // 16 slabs, 2 per iteration
            const int i0 = ii * 2;
            __syncthreads();                // drains buf0's loads
            STAGE(As1, Bs1, (i0 + 1) * BK); // slab i0+1 -> buf1 (always valid, i0<=14)
            COMPUTE(As0, Bs0);
            __syncthreads();                // drains buf1's loads; all As0 reads done
            if (i0 + 2 < 16) STAGE(As0, Bs0, (i0 + 2) * BK);
            COMPUTE(As1, Bs1);
        }

        // grab next tile (overlap the atomic with the epilogue)
        if (tid == 0)
            next_tile_sh = PGRID + atomicAdd(steal_cnt, 1);

        // epilogue: C/D layout col=lane&15, row=quad*4+reg (m89-verified); mask partials
#pragma unroll
        for (int mi = 0; mi < 4; ++mi) {
            const int rbase = m0 + wm + mi * 16 + quad * 4;
#pragma unroll
            for (int ni = 0; ni < 4; ++ni) {
                const int col = n0 + wn + ni * 16 + fr;
#pragma unroll
                for (int j = 0; j < 4; ++j) {
                    const int row = rbase + j;
                    if (row < seg_end)
                        c[(size_t)row * NDIM + col] = acc[mi][ni][j];
                }
            }
        }
        __syncthreads();                    // next_tile_sh visible; LDS safe to reuse
        tile = next_tile_sh;
#undef STAGE
#undef COMPUTE
    }
}

extern "C" void kernel_launch(void* const* d_in, const int* in_sizes, int n_in,
                              void* d_out, int out_size, void* d_ws, size_t ws_size,
                              hipStream_t stream) {
    const float* a          = (const float*)d_in[0];
    const float* b          = (const float*)d_in[1];
    // d_in[2]=c (zeros; fully overwritten), d_in[3]=batch_size, d_in[4]=weight_column_major: unused
    const int*   seg_indptr = (const int*)d_in[5];
    const int*   widx       = (const int*)d_in[6];
    float*       out        = (float*)d_out;

    unsigned short* wa  = (unsigned short*)d_ws;                 // [M,K] bf16 (16 MiB)
    unsigned short* wb  = wa + (size_t)MDIM * KDIM;              // [E,N,K] bf16 (16 MiB)
    int*            cnt = (int*)(wb + (size_t)NEXP * NDIM * KDIM);  // steal counter

    hipMemsetAsync(cnt, 0, sizeof(int), stream);                 // graph-capturable
    hipLaunchKernelGGL(cvt_bf16, dim3(8192), dim3(256), 0, stream, a, b, wa, wb);
    hipLaunchKernelGGL(grouped_gemm_v7, dim3(PGRID), dim3(256), 0, stream,
                       wa, wb, seg_indptr, widx, out, cnt);
}

// Round 8
// 167.397 us; speedup vs baseline: 1.1574x; 1.0307x over previous
//
#include <hip/hip_runtime.h>
#include <hip/hip_bf16.h>
#include <stdint.h>

#define MDIM 8192
#define KDIM 1024
#define NDIM 1024
#define NEXP 8
// virtual row space: rows 0..8191 = a, rows 8192..16383 = b (E*N = 8192)
// fragment = 16 rows x 32 k of bf16, stored as 1KB: lane l's 16B at frag*1024 + l*16
// frag id f = (vrow/16)*32 + (k/32); elem offset = f*512 + l*8

typedef __attribute__((ext_vector_type(8))) short bf16x8;
typedef __attribute__((ext_vector_type(4))) float floatx4;
typedef __attribute__((ext_vector_type(8))) unsigned short ushort8;

static __device__ __forceinline__ unsigned short f2b(float f) {
    // fp32 -> bf16 round-to-nearest-even (inputs finite)
    unsigned int u = __float_as_uint(f);
    return (unsigned short)((u + 0x7fffu + ((u >> 16) & 1u)) >> 16);
}

// ---------------- pass 1: fp32 -> bf16 fragment-major transpose ----------------
// one thread per (frag, lane) slot: 32768 frags x 64 = 2,097,152 thr = 8192 blocks.
// writes perfectly coalesced (consecutive threads -> consecutive 16B); reads are
// 128B-line granular (each fp32 line = exactly one frag's k-range, fully consumed).
__global__ __launch_bounds__(256)
void cvt_frag(const float* __restrict__ a, const float* __restrict__ b,
              unsigned short* __restrict__ w)
{
    const int t = (int)blockIdx.x * 256 + (int)threadIdx.x;
    const int f = t >> 6, l = t & 63;
    const int vrow = ((f >> 5) << 4) + (l & 15);       // frag-row*16 + (lane&15)
    const int kk   = ((f & 31) << 5) + ((l >> 4) << 3); // j*32 + quad*8
    const float* __restrict__ src = (vrow < MDIM)
        ? a + (size_t)vrow * KDIM + kk
        : b + (size_t)(vrow - MDIM) * KDIM + kk;
    const float4 lo = *reinterpret_cast<const float4*>(src);
    const float4 hi = *reinterpret_cast<const float4*>(src + 4);
    ushort8 o;
    o[0] = f2b(lo.x); o[1] = f2b(lo.y); o[2] = f2b(lo.z); o[3] = f2b(lo.w);
    o[4] = f2b(hi.x); o[5] = f2b(hi.y); o[6] = f2b(hi.z); o[7] = f2b(hi.w);
    *reinterpret_cast<ushort8*>(w + (size_t)f * 512 + l * 8) = o;
}

// ---------------- pass 2: barrier-free frag-major GEMM -------------------------
// 4 waves/block in 2x2, each wave a 64x64 tile: per k-step 8 coalesced 1KB
// frag loads + 16 MFMA, register dbuf. No LDS, no __syncthreads -> compiler
// emits fine-grained s_waitcnt vmcnt(8) with the next slab's loads in flight.
__global__ __launch_bounds__(256, 3)   // 3 blocks/CU -> all 568 blocks resident, no tail
void grouped_gemm_frag(const unsigned short* __restrict__ W,
                       const int* __restrict__ seg_indptr,
                       const int* __restrict__ widx,
                       float* __restrict__ c)
{
    // XCD m-band swizzle: 576 = 8*72; XCD x owns consecutive tiles x*72..x*72+71
    const int bid = ((int)blockIdx.x & 7) * 72 + ((int)blockIdx.x >> 3);

    // tile decode; each segment's tiles start at align16(seg_start) so frag rows align.
    // rows in [align16(ps), ps) are computed with the wrong expert but masked at store;
    // the previous segment's last tile owns and stores them.
    int rem = bid;
    int s = -1, m0 = 0, n0 = 0, seg_s = 0, seg_e = 0;
    for (int i = 0; i < NEXP; ++i) {
        int ps = seg_indptr[i], pe = seg_indptr[i + 1];
        int start = ps & ~15;
        int nt = ((pe - start + 127) >> 7) * 8;
        if (rem < nt) { s = i; m0 = start + (rem >> 3) * 128; n0 = (rem & 7) * 128; seg_s = ps; seg_e = pe; break; }
        rem -= nt;
    }
    if (s < 0) return;  // surplus block (worst-case grid)

    const int wave = (int)threadIdx.x >> 6;
    const int lane = (int)threadIdx.x & 63;
    const int wm = (wave & 1) * 64;
    const int wn = (wave >> 1) * 64;
    const int fr   = lane & 15;
    const int quad = lane >> 4;

    // frag-row bases. A reads past row 8192 (tail tiles) land in B's frag region of W
    // (valid memory, masked at store). m0+wm <= 8255, frag rows < 16384: in bounds.
    const size_t ia  = (size_t)((m0 + wm) >> 4);
    const size_t ibv = (size_t)((MDIM + widx[s] * NDIM + n0 + wn) >> 4);
    const unsigned short* __restrict__ ap = W + ia  * 16384 + lane * 8;  // frag-row stride = 32 frags * 512
    const unsigned short* __restrict__ bp = W + ibv * 16384 + lane * 8;

    floatx4 acc[4][4] = {};
    bf16x8 af[2][4], bf[2][4];

#pragma unroll
    for (int t = 0; t < 4; ++t) {          // prologue: k-step 0 -> buf0
        af[0][t] = *reinterpret_cast<const bf16x8*>(ap + t * 16384);
        bf[0][t] = *reinterpret_cast<const bf16x8*>(bp + t * 16384);
    }

#pragma unroll 1
    for (int j = 0; j < 32; j += 2) {
        // prefetch k-step j+1 into buf1 (loads fly over the buf0 MFMA block)
#pragma unroll
        for (int t = 0; t < 4; ++t) {
            af[1][t] = *reinterpret_cast<const bf16x8*>(ap + t * 16384 + (j + 1) * 512);
            bf[1][t] = *reinterpret_cast<const bf16x8*>(bp + t * 16384 + (j + 1) * 512);
        }
#pragma unroll
        for (int mi = 0; mi < 4; ++mi)
#pragma unroll
            for (int ni = 0; ni < 4; ++ni)
                acc[mi][ni] = __builtin_amdgcn_mfma_f32_16x16x32_bf16(af[0][mi], bf[0][ni], acc[mi][ni], 0, 0, 0);

        const int jn = (j + 2 < 32) ? (j + 2) : 0;   // branchless dummy wrap on last iter
#pragma unroll
        for (int t = 0; t < 4; ++t) {
            af[0][t] = *reinterpret_cast<const bf16x8*>(ap + t * 16384 + jn * 512);
            bf[0][t] = *reinterpret_cast<const bf16x8*>(bp + t * 16384 + jn * 512);
        }
#pragma unroll
        for (int mi = 0; mi < 4; ++mi)
#pragma unroll
            for (int ni = 0; ni < 4; ++ni)
                acc[mi][ni] = __builtin_amdgcn_mfma_f32_16x16x32_bf16(af[1][mi], bf[1][ni], acc[mi][ni], 0, 0, 0);
    }

    // epilogue: C/D layout col=lane&15, row=quad*4+reg (m89-verified);
    // mask both segment edges (tiles are 16-aligned, not segment-aligned)
#pragma unroll
    for (int mi = 0; mi < 4; ++mi) {
        const int rbase = m0 + wm + mi * 16 + quad * 4;
#pragma unroll
        for (int ni = 0; ni < 4; ++ni) {
            const int col = n0 + wn + ni * 16 + fr;
#pragma unroll
            for (int j = 0; j < 4; ++j) {
                const int row = rbase + j;
                if (row >= seg_s && row < seg_e)
                    c[(size_t)row * NDIM + col] = acc[mi][ni][j];
            }
        }
    }
}

extern "C" void kernel_launch(void* const* d_in, const int* in_sizes, int n_in,
                              void* d_out, int out_size, void* d_ws, size_t ws_size,
                              hipStream_t stream) {
    const float* a          = (const float*)d_in[0];
    const float* b          = (const float*)d_in[1];
    // d_in[2]=c (zeros; fully overwritten), d_in[3]=batch_size, d_in[4]=weight_column_major: unused
    const int*   seg_indptr = (const int*)d_in[5];
    const int*   widx       = (const int*)d_in[6];
    float*       out        = (float*)d_out;

    unsigned short* w = (unsigned short*)d_ws;   // 32 MiB frag-major bf16 (a then b)

    hipLaunchKernelGGL(cvt_frag, dim3(8192), dim3(256), 0, stream, a, b, w);
    // worst-case tiles: sum ceil((len_s+15)/128) <= 64+8 = 72 m-tiles x 8 n-tiles = 576 = 8*72
    hipLaunchKernelGGL(grouped_gemm_frag, dim3(576), dim3(256), 0, stream,
                       w, seg_indptr, widx, out);
}